// Round 1
// baseline (251.069 us; speedup 1.0000x reference)
//
#include <hip/hip_runtime.h>
#include <stdint.h>

#define B_SZ 4096
#define D_SZ 512
#define SHIFT 64.0f

typedef __attribute__((ext_vector_type(8))) short short8;
typedef __attribute__((ext_vector_type(4))) float floatx4;
typedef unsigned short u16;
typedef unsigned int u32;

__device__ __forceinline__ u16 f2bf(float f) {
    u32 u = __float_as_uint(f);
    u32 r = (u + 0x7FFFu + ((u >> 16) & 1u)) >> 16;   // RNE, inputs are finite
    return (u16)r;
}

// ---- K1: fp32 -> bf16 convert, plus per-row time/norm. One wave per row. ----
__global__ __launch_bounds__(256) void prep_kernel(
    const float* __restrict__ img, const float* __restrict__ dna,
    const float* __restrict__ txt, const float* __restrict__ curv_p,
    u16* __restrict__ bf, float* __restrict__ times, float* __restrict__ norms) {
    int wave = (blockIdx.x * blockDim.x + threadIdx.x) >> 6;  // 0..12287
    int lane = threadIdx.x & 63;
    const float* src = (wave < B_SZ) ? img : (wave < 2 * B_SZ) ? dna : txt;
    int row = wave & (B_SZ - 1);
    const float* p = src + row * D_SZ + lane * 8;
    float4 v0 = *(const float4*)(p);
    float4 v1 = *(const float4*)(p + 4);
    float ss = v0.x*v0.x + v0.y*v0.y + v0.z*v0.z + v0.w*v0.w
             + v1.x*v1.x + v1.y*v1.y + v1.z*v1.z + v1.w*v1.w;
    uint4 pk;
    pk.x = (u32)f2bf(v0.x) | ((u32)f2bf(v0.y) << 16);
    pk.y = (u32)f2bf(v0.z) | ((u32)f2bf(v0.w) << 16);
    pk.z = (u32)f2bf(v1.x) | ((u32)f2bf(v1.y) << 16);
    pk.w = (u32)f2bf(v1.z) | ((u32)f2bf(v1.w) << 16);
    *(uint4*)(bf + wave * D_SZ + lane * 8) = pk;
    #pragma unroll
    for (int m = 1; m < 64; m <<= 1) ss += __shfl_xor(ss, m);
    if (lane == 0) {
        float curv = curv_p[0];
        times[wave] = sqrtf(1.0f / curv + ss);
        norms[wave] = sqrtf(ss);
    }
}

// ---- label histogram: S_n = hist[label[n]] ----
__global__ __launch_bounds__(256) void hist_kernel(const int* __restrict__ labels,
                                                   int* __restrict__ hist) {
    int i = blockIdx.x * blockDim.x + threadIdx.x;
    if (i < B_SZ) atomicAdd(&hist[labels[i]], 1);
}

// ---- K2: batched bf16 MFMA GEMM (A·B^T) with fused hyperbolic-CE epilogue ----
// z=0: (img,dna)  z=1: (img,txt)  z=2: (dna,txt)
__global__ __launch_bounds__(256) void gemm_epi_kernel(
    const u16* __restrict__ bf, const float* __restrict__ times,
    const int* __restrict__ labels,
    const float* __restrict__ ls_p, const float* __restrict__ curv_p,
    float* __restrict__ rsum_e, float* __restrict__ rsum_t,
    float* __restrict__ csum_e, float* __restrict__ csum_t) {
    __shared__ u16 sA[128 * 32];
    __shared__ u16 sB[128 * 32];

    int z = blockIdx.z;
    int pa = (z == 2) ? 1 : 0;
    int pb = (z == 0) ? 1 : 2;
    const u16* A  = bf + pa * (B_SZ * D_SZ);
    const u16* Bm = bf + pb * (B_SZ * D_SZ);

    int t = threadIdx.x;
    int rowBlk = blockIdx.y * 128;
    int colBlk = blockIdx.x * 128;

    // staging: thread t owns 16B chunks t and t+256 of each 128x32 tile
    int srow = t >> 2;       // 0..63
    int sk8  = t & 3;        // 16B chunk within 64B row
    const uint4* gA0 = (const uint4*)(A  + (rowBlk + srow)      * D_SZ + sk8 * 8);
    const uint4* gA1 = (const uint4*)(A  + (rowBlk + srow + 64) * D_SZ + sk8 * 8);
    const uint4* gB0 = (const uint4*)(Bm + (colBlk + srow)      * D_SZ + sk8 * 8);
    const uint4* gB1 = (const uint4*)(Bm + (colBlk + srow + 64) * D_SZ + sk8 * 8);
    uint4* sA4 = (uint4*)sA;
    uint4* sB4 = (uint4*)sB;
    int d0 = srow * 4 + (sk8 ^ (srow & 3));   // XOR chunk swizzle
    int d1 = d0 + 256;                        // (srow+64)&3 == srow&3

    int wave = t >> 6, lane = t & 63;
    int wr = wave >> 1, wc = wave & 1;
    int q = lane >> 4, s = lane & 15;

    floatx4 acc[4][4];
    #pragma unroll
    for (int i = 0; i < 4; ++i)
        #pragma unroll
        for (int j = 0; j < 4; ++j) acc[i][j] = (floatx4){0.f, 0.f, 0.f, 0.f};

    for (int kt = 0; kt < D_SZ / 32; ++kt) {
        uint4 a0 = gA0[kt * 4];
        uint4 a1 = gA1[kt * 4];
        uint4 b0 = gB0[kt * 4];
        uint4 b1 = gB1[kt * 4];
        __syncthreads();                 // prior iter's frag reads done
        sA4[d0] = a0; sA4[d1] = a1;
        sB4[d0] = b0; sB4[d1] = b1;
        __syncthreads();
        short8 af[4], bfr[4];
        #pragma unroll
        for (int i = 0; i < 4; ++i) {
            int r = wr * 64 + i * 16 + s;
            af[i] = *(const short8*)&sA[(r * 4 + (q ^ (r & 3))) * 8];
        }
        #pragma unroll
        for (int j = 0; j < 4; ++j) {
            int r = wc * 64 + j * 16 + s;
            bfr[j] = *(const short8*)&sB[(r * 4 + (q ^ (r & 3))) * 8];
        }
        #pragma unroll
        for (int i = 0; i < 4; ++i)
            #pragma unroll
            for (int j = 0; j < 4; ++j)
                acc[i][j] = __builtin_amdgcn_mfma_f32_16x16x32_bf16(af[i], bfr[j], acc[i][j], 0, 0, 0);
    }

    // ---- fused epilogue: logit = -ls*acosh(curv*(ta*tb - G))/sqrt(curv) ----
    float ls = ls_p[0];
    float curv = curv_p[0];
    float rsc = rsqrtf(curv);
    const float* tA = times + pa * B_SZ;
    const float* tB = times + pb * B_SZ;

    int rowbase = rowBlk + wr * 64;
    int colbase = colBlk + wc * 64;

    float tb[4]; int lb[4]; int mcol[4];
    #pragma unroll
    for (int j = 0; j < 4; ++j) {
        mcol[j] = colbase + j * 16 + s;
        tb[j] = tB[mcol[j]];
        lb[j] = labels[mcol[j]];
    }
    float colE[4] = {0.f, 0.f, 0.f, 0.f}, colT[4] = {0.f, 0.f, 0.f, 0.f};

    float* rsE = rsum_e + z * B_SZ;
    float* rsT = rsum_t + z * B_SZ;
    float* csE = csum_e + z * B_SZ;
    float* csT = csum_t + z * B_SZ;

    #pragma unroll
    for (int i = 0; i < 4; ++i) {
        int nb = rowbase + i * 16 + q * 4;   // this lane's 4 C rows
        float ta[4]; int la[4];
        #pragma unroll
        for (int r = 0; r < 4; ++r) { ta[r] = tA[nb + r]; la[r] = labels[nb + r]; }
        float re[4] = {0.f, 0.f, 0.f, 0.f}, rt[4] = {0.f, 0.f, 0.f, 0.f};
        #pragma unroll
        for (int j = 0; j < 4; ++j) {
            floatx4 a = acc[i][j];
            #pragma unroll
            for (int r = 0; r < 4; ++r) {
                float G = a[r];
                float zc = curv * (ta[r] * tb[j] - G);     // c_xyl >= 1
                zc = fmaxf(zc, 1.0f + 1e-8f);
                float d = __logf(zc + sqrtf(zc * zc - 1.0f)) * rsc;
                float logit = -ls * d;
                float e = __expf(logit + SHIFT);
                float tl = (la[r] == lb[j]) ? logit : 0.0f;
                re[r] += e; rt[r] += tl;
                colE[j] += e; colT[j] += tl;
            }
        }
        #pragma unroll
        for (int r = 0; r < 4; ++r) {   // reduce over 16 lanes of each quad-group
            #pragma unroll
            for (int m = 1; m <= 8; m <<= 1) {
                re[r] += __shfl_xor(re[r], m);
                rt[r] += __shfl_xor(rt[r], m);
            }
        }
        #pragma unroll
        for (int r = 0; r < 4; ++r) {
            if (s == r) {   // one lane per quad-group writes its row
                atomicAdd(&rsE[nb + r], re[r]);
                atomicAdd(&rsT[nb + r], rt[r]);
            }
        }
    }
    #pragma unroll
    for (int j = 0; j < 4; ++j) {       // reduce over the 4 quad-groups
        colE[j] += __shfl_xor(colE[j], 16); colE[j] += __shfl_xor(colE[j], 32);
        colT[j] += __shfl_xor(colT[j], 16); colT[j] += __shfl_xor(colT[j], 32);
        if (q == 0) {
            atomicAdd(&csE[mcol[j]], colE[j]);
            atomicAdd(&csT[mcol[j]], colT[j]);
        }
    }
}

// ---- entailment(dna -> image), fp32, one wave per row (16 rows per wave) ----
__global__ __launch_bounds__(256) void entail_kernel(
    const float* __restrict__ dna, const float* __restrict__ img,
    const float* __restrict__ times, const float* __restrict__ norms,
    const float* __restrict__ curv_p, float* __restrict__ ent_acc) {
    int wave = (blockIdx.x * blockDim.x + threadIdx.x) >> 6;  // 0..255
    int lane = threadIdx.x & 63;
    float curv = curv_p[0];
    const float* tD = times + B_SZ;      // dna times
    const float* tI = times;             // image times
    const float* nD = norms + B_SZ;      // dna norms
    float local = 0.0f;
    for (int rr = 0; rr < 16; ++rr) {
        int row = wave * 16 + rr;
        const float* x = dna + row * D_SZ + lane * 8;
        const float* y = img + row * D_SZ + lane * 8;
        float4 x0 = *(const float4*)x, x1 = *(const float4*)(x + 4);
        float4 y0 = *(const float4*)y, y1 = *(const float4*)(y + 4);
        float dot = x0.x*y0.x + x0.y*y0.y + x0.z*y0.z + x0.w*y0.w
                  + x1.x*y1.x + x1.y*y1.y + x1.z*y1.z + x1.w*y1.w;
        #pragma unroll
        for (int m = 1; m < 64; m <<= 1) dot += __shfl_xor(dot, m);
        if (lane == 0) {
            float xt = tD[row], yt = tI[row], nx = nD[row];
            float c = curv * (dot - xt * yt);                       // <= -1
            float numer = yt + c * xt;
            float denom = nx * sqrtf(fmaxf(c * c - 1.0f, 0.0f));
            float ai = numer / (denom + 1e-8f);
            ai = fminf(fmaxf(ai, -1.0f + 1e-8f), 1.0f - 1e-8f);
            float ang = acosf(ai);
            float as_in = 0.2f / (nx * sqrtf(curv) + 1e-6f);        // 2*min_radius
            as_in = fminf(fmaxf(as_in, -1.0f + 1e-6f), 1.0f - 1e-6f);
            float ap = asinf(as_in);
            local += fmaxf(ang - ap, 0.0f);
        }
    }
    if (lane == 0) atomicAdd(ent_acc, local);
}

// ---- finalize: CE assembly ----
__global__ __launch_bounds__(256) void finalize1(
    const float* __restrict__ rsum_e, const float* __restrict__ rsum_t,
    const float* __restrict__ csum_e, const float* __restrict__ csum_t,
    const int* __restrict__ labels, const int* __restrict__ hist,
    float* __restrict__ ce_acc) {
    int n = blockIdx.x * blockDim.x + threadIdx.x;
    float part = 0.0f;
    if (n < B_SZ) {
        float Sn = (float)hist[labels[n]];
        #pragma unroll
        for (int p = 0; p < 3; ++p) {
            float lseR = __logf(rsum_e[p * B_SZ + n]) - SHIFT;
            float lseC = __logf(csum_e[p * B_SZ + n]) - SHIFT;
            part += Sn * lseR - rsum_t[p * B_SZ + n];
            part += Sn * lseC - csum_t[p * B_SZ + n];
        }
    }
    #pragma unroll
    for (int m = 1; m < 64; m <<= 1) part += __shfl_xor(part, m);
    if ((threadIdx.x & 63) == 0) atomicAdd(ce_acc, part);
}

__global__ void finalize2(const float* __restrict__ ce_acc,
                          const float* __restrict__ ent_acc,
                          float* __restrict__ out) {
    float contr = ce_acc[0] / (6.0f * (float)B_SZ);
    float ent = ent_acc[0] / (float)B_SZ;
    out[0] = contr + 0.2f * ent;
    out[1] = contr;
    out[2] = ent;
}

// ---- workspace layout (bytes) ----
//   0        : bf16 feats, 3*4096*512*2 = 12,582,912
//   12582912 : times[3][4096] f32        (49,152)
//   12632064 : norms[3][4096] f32        (49,152)
//   12681216 : rsum_e[3][4096] f32       (49,152)   <- zeroed each launch
//   12730368 : rsum_t[3][4096] f32       (49,152)
//   12779520 : csum_e[3][4096] f32       (49,152)
//   12828672 : csum_t[3][4096] f32       (49,152)
//   12877824 : hist[512] int             (2,048)
//   12879872 : ce_acc f32, 12879876 : ent_acc f32
extern "C" void kernel_launch(void* const* d_in, const int* in_sizes, int n_in,
                              void* d_out, int out_size, void* d_ws, size_t ws_size,
                              hipStream_t stream) {
    const float* img    = (const float*)d_in[0];
    const float* dna    = (const float*)d_in[1];
    const float* txt    = (const float*)d_in[2];
    const int*   labels = (const int*)d_in[3];
    const float* ls     = (const float*)d_in[4];
    const float* curv   = (const float*)d_in[5];

    char* ws = (char*)d_ws;
    u16*   bf     = (u16*)ws;
    float* times  = (float*)(ws + 12582912);
    float* norms  = (float*)(ws + 12632064);
    float* rsum_e = (float*)(ws + 12681216);
    float* rsum_t = (float*)(ws + 12730368);
    float* csum_e = (float*)(ws + 12779520);
    float* csum_t = (float*)(ws + 12828672);
    int*   hist   = (int*)  (ws + 12877824);
    float* ce_acc = (float*)(ws + 12879872);
    float* ent_acc= (float*)(ws + 12879876);

    hipMemsetAsync(ws + 12681216, 0, 198664, stream);  // accumulators + hist + scalars

    prep_kernel<<<3072, 256, 0, stream>>>(img, dna, txt, curv, bf, times, norms);
    hist_kernel<<<16, 256, 0, stream>>>(labels, hist);
    dim3 g(32, 32, 3);
    gemm_epi_kernel<<<g, 256, 0, stream>>>(bf, times, labels, ls, curv,
                                           rsum_e, rsum_t, csum_e, csum_t);
    entail_kernel<<<64, 256, 0, stream>>>(dna, img, times, norms, curv, ent_acc);
    finalize1<<<16, 256, 0, stream>>>(rsum_e, rsum_t, csum_e, csum_t, labels, hist, ce_acc);
    finalize2<<<1, 1, 0, stream>>>(ce_acc, ent_acc, (float*)d_out);
}

// Round 2
// 247.150 us; speedup vs baseline: 1.0159x; 1.0159x over previous
//
#include <hip/hip_runtime.h>
#include <stdint.h>

#define B_SZ 4096
#define D_SZ 512
#define SHIFT 64.0f

typedef __attribute__((ext_vector_type(8))) short short8;
typedef __attribute__((ext_vector_type(4))) float floatx4;
typedef unsigned short u16;
typedef unsigned int u32;

#define GLD_LDS16(gp, sp)                                                              \
    __builtin_amdgcn_global_load_lds(                                                  \
        (const __attribute__((address_space(1))) void*)(gp),                           \
        (__attribute__((address_space(3))) void*)(sp), 16, 0, 0)

__device__ __forceinline__ u16 f2bf(float f) {
    u32 u = __float_as_uint(f);
    u32 r = (u + 0x7FFFu + ((u >> 16) & 1u)) >> 16;   // RNE, inputs are finite
    return (u16)r;
}

// ---- K1: fp32 -> bf16 convert, per-row time/norm, fused label histogram ----
__global__ __launch_bounds__(256) void prep_kernel(
    const float* __restrict__ img, const float* __restrict__ dna,
    const float* __restrict__ txt, const float* __restrict__ curv_p,
    const int* __restrict__ labels, int* __restrict__ hist,
    u16* __restrict__ bf, float* __restrict__ times, float* __restrict__ norms) {
    int gid = blockIdx.x * blockDim.x + threadIdx.x;
    if (gid < B_SZ) atomicAdd(&hist[labels[gid]], 1);   // fused histogram
    int wave = gid >> 6;  // 0..12287
    int lane = threadIdx.x & 63;
    const float* src = (wave < B_SZ) ? img : (wave < 2 * B_SZ) ? dna : txt;
    int row = wave & (B_SZ - 1);
    const float* p = src + row * D_SZ + lane * 8;
    float4 v0 = *(const float4*)(p);
    float4 v1 = *(const float4*)(p + 4);
    float ss = v0.x*v0.x + v0.y*v0.y + v0.z*v0.z + v0.w*v0.w
             + v1.x*v1.x + v1.y*v1.y + v1.z*v1.z + v1.w*v1.w;
    uint4 pk;
    pk.x = (u32)f2bf(v0.x) | ((u32)f2bf(v0.y) << 16);
    pk.y = (u32)f2bf(v0.z) | ((u32)f2bf(v0.w) << 16);
    pk.z = (u32)f2bf(v1.x) | ((u32)f2bf(v1.y) << 16);
    pk.w = (u32)f2bf(v1.z) | ((u32)f2bf(v1.w) << 16);
    *(uint4*)(bf + wave * D_SZ + lane * 8) = pk;
    #pragma unroll
    for (int m = 1; m < 64; m <<= 1) ss += __shfl_xor(ss, m);
    if (lane == 0) {
        float curv = curv_p[0];
        times[wave] = sqrtf(1.0f / curv + ss);
        norms[wave] = sqrtf(ss);
    }
}

// ---- K2: batched bf16 MFMA GEMM (A·B^T), global_load_lds + LDS double-buffer,
//          fused hyperbolic-CE epilogue. z=0:(img,dna) z=1:(img,txt) z=2:(dna,txt)
__global__ __launch_bounds__(256) void gemm_epi_kernel(
    const u16* __restrict__ bf, const float* __restrict__ times,
    const int* __restrict__ labels,
    const float* __restrict__ ls_p, const float* __restrict__ curv_p,
    float* __restrict__ rsum_e, float* __restrict__ rsum_t,
    float* __restrict__ csum_e, float* __restrict__ csum_t) {
    __shared__ u16 sA[2][128 * 32];
    __shared__ u16 sB[2][128 * 32];

    int z = blockIdx.z;
    int pa = (z == 2) ? 1 : 0;
    int pb = (z == 0) ? 1 : 2;
    const u16* A  = bf + pa * (B_SZ * D_SZ);
    const u16* Bm = bf + pb * (B_SZ * D_SZ);

    int t = threadIdx.x;
    int rowBlk = blockIdx.y * 128;
    int colBlk = blockIdx.x * 128;
    int wave = t >> 6, lane = t & 63;

    // --- staging: each wave issues 4 global_load_lds (16B/lane, 1KB/instr).
    // LDS dest is base + lane*16 (fixed); XOR chunk swizzle applied on the
    // SOURCE side so frag-read addressing matches the verified R1 layout:
    // slot(row r, chunk c) = r*4 + (c ^ (r&3)).
    int lrow = lane >> 2;                 // row within 16-row group
    int lch  = (lane & 3) ^ (lrow & 3);   // swizzled source chunk
    int g0 = wave, g1 = wave + 4;         // this wave's two 16-row groups
    const u16* gA0 = A  + (rowBlk + g0 * 16 + lrow) * D_SZ + lch * 8;
    const u16* gA1 = A  + (rowBlk + g1 * 16 + lrow) * D_SZ + lch * 8;
    const u16* gB0 = Bm + (colBlk + g0 * 16 + lrow) * D_SZ + lch * 8;
    const u16* gB1 = Bm + (colBlk + g1 * 16 + lrow) * D_SZ + lch * 8;

    int wr = wave >> 1, wc = wave & 1;
    int q = lane >> 4, s = lane & 15;

    floatx4 acc[4][4];
    #pragma unroll
    for (int i = 0; i < 4; ++i)
        #pragma unroll
        for (int j = 0; j < 4; ++j) acc[i][j] = (floatx4){0.f, 0.f, 0.f, 0.f};

    // prologue: stage kt=0 into buffer 0
    {
        GLD_LDS16(gA0, &sA[0][g0 * 512]);
        GLD_LDS16(gA1, &sA[0][g1 * 512]);
        GLD_LDS16(gB0, &sB[0][g0 * 512]);
        GLD_LDS16(gB1, &sB[0][g1 * 512]);
    }

    for (int kt = 0; kt < D_SZ / 32; ++kt) {
        int cur = kt & 1;
        __syncthreads();   // drains vmcnt(0): buf[cur] loads landed; prior frag reads done
        if (kt < D_SZ / 32 - 1) {
            int ko = (kt + 1) * 32;
            int nxt = cur ^ 1;
            GLD_LDS16(gA0 + ko, &sA[nxt][g0 * 512]);
            GLD_LDS16(gA1 + ko, &sA[nxt][g1 * 512]);
            GLD_LDS16(gB0 + ko, &sB[nxt][g0 * 512]);
            GLD_LDS16(gB1 + ko, &sB[nxt][g1 * 512]);
        }
        short8 af[4], bfr[4];
        #pragma unroll
        for (int i = 0; i < 4; ++i) {
            int r = wr * 64 + i * 16 + s;
            af[i] = *(const short8*)&sA[cur][(r * 4 + (q ^ (r & 3))) * 8];
        }
        #pragma unroll
        for (int j = 0; j < 4; ++j) {
            int r = wc * 64 + j * 16 + s;
            bfr[j] = *(const short8*)&sB[cur][(r * 4 + (q ^ (r & 3))) * 8];
        }
        #pragma unroll
        for (int i = 0; i < 4; ++i)
            #pragma unroll
            for (int j = 0; j < 4; ++j)
                acc[i][j] = __builtin_amdgcn_mfma_f32_16x16x32_bf16(af[i], bfr[j], acc[i][j], 0, 0, 0);
    }

    // ---- fused epilogue: logit = -ls*acosh(curv*(ta*tb - G))/sqrt(curv) ----
    float ls = ls_p[0];
    float curv = curv_p[0];
    float rsc = rsqrtf(curv);
    const float* tA = times + pa * B_SZ;
    const float* tB = times + pb * B_SZ;

    int rowbase = rowBlk + wr * 64;
    int colbase = colBlk + wc * 64;

    float tb[4]; int lb[4]; int mcol[4];
    #pragma unroll
    for (int j = 0; j < 4; ++j) {
        mcol[j] = colbase + j * 16 + s;
        tb[j] = tB[mcol[j]];
        lb[j] = labels[mcol[j]];
    }
    float colE[4] = {0.f, 0.f, 0.f, 0.f}, colT[4] = {0.f, 0.f, 0.f, 0.f};

    float* rsE = rsum_e + z * B_SZ;
    float* rsT = rsum_t + z * B_SZ;
    float* csE = csum_e + z * B_SZ;
    float* csT = csum_t + z * B_SZ;

    #pragma unroll
    for (int i = 0; i < 4; ++i) {
        int nb = rowbase + i * 16 + q * 4;   // this lane's 4 C rows
        float ta[4]; int la[4];
        #pragma unroll
        for (int r = 0; r < 4; ++r) { ta[r] = tA[nb + r]; la[r] = labels[nb + r]; }
        float re[4] = {0.f, 0.f, 0.f, 0.f}, rt[4] = {0.f, 0.f, 0.f, 0.f};
        #pragma unroll
        for (int j = 0; j < 4; ++j) {
            floatx4 a = acc[i][j];
            #pragma unroll
            for (int r = 0; r < 4; ++r) {
                float G = a[r];
                float zc = curv * (ta[r] * tb[j] - G);     // c_xyl >= 1
                zc = fmaxf(zc, 1.0f + 1e-8f);
                float d = __logf(zc + sqrtf(zc * zc - 1.0f)) * rsc;
                float logit = -ls * d;
                float e = __expf(logit + SHIFT);
                float tl = (la[r] == lb[j]) ? logit : 0.0f;
                re[r] += e; rt[r] += tl;
                colE[j] += e; colT[j] += tl;
            }
        }
        #pragma unroll
        for (int r = 0; r < 4; ++r) {   // reduce over 16 lanes of each quad-group
            #pragma unroll
            for (int m = 1; m <= 8; m <<= 1) {
                re[r] += __shfl_xor(re[r], m);
                rt[r] += __shfl_xor(rt[r], m);
            }
        }
        #pragma unroll
        for (int r = 0; r < 4; ++r) {
            if (s == r) {   // one lane per quad-group writes its row
                atomicAdd(&rsE[nb + r], re[r]);
                atomicAdd(&rsT[nb + r], rt[r]);
            }
        }
    }
    #pragma unroll
    for (int j = 0; j < 4; ++j) {       // reduce over the 4 quad-groups
        colE[j] += __shfl_xor(colE[j], 16); colE[j] += __shfl_xor(colE[j], 32);
        colT[j] += __shfl_xor(colT[j], 16); colT[j] += __shfl_xor(colT[j], 32);
        if (q == 0) {
            atomicAdd(&csE[mcol[j]], colE[j]);
            atomicAdd(&csT[mcol[j]], colT[j]);
        }
    }
}

// ---- entailment(dna -> image), fp32, one wave per 4 rows ----
__global__ __launch_bounds__(256) void entail_kernel(
    const float* __restrict__ dna, const float* __restrict__ img,
    const float* __restrict__ times, const float* __restrict__ norms,
    const float* __restrict__ curv_p, float* __restrict__ ent_acc) {
    int wv = (blockIdx.x * blockDim.x + threadIdx.x) >> 6;  // 0..1023
    int lane = threadIdx.x & 63;
    float curv = curv_p[0];
    const float* tD = times + B_SZ;      // dna times
    const float* tI = times;             // image times
    const float* nD = norms + B_SZ;      // dna norms
    float local = 0.0f;
    for (int rr = 0; rr < 4; ++rr) {
        int row = wv * 4 + rr;
        const float* x = dna + row * D_SZ + lane * 8;
        const float* y = img + row * D_SZ + lane * 8;
        float4 x0 = *(const float4*)x, x1 = *(const float4*)(x + 4);
        float4 y0 = *(const float4*)y, y1 = *(const float4*)(y + 4);
        float dot = x0.x*y0.x + x0.y*y0.y + x0.z*y0.z + x0.w*y0.w
                  + x1.x*y1.x + x1.y*y1.y + x1.z*y1.z + x1.w*y1.w;
        #pragma unroll
        for (int m = 1; m < 64; m <<= 1) dot += __shfl_xor(dot, m);
        if (lane == 0) {
            float xt = tD[row], yt = tI[row], nx = nD[row];
            float c = curv * (dot - xt * yt);                       // <= -1
            float numer = yt + c * xt;
            float denom = nx * sqrtf(fmaxf(c * c - 1.0f, 0.0f));
            float ai = numer / (denom + 1e-8f);
            ai = fminf(fmaxf(ai, -1.0f + 1e-8f), 1.0f - 1e-8f);
            float ang = acosf(ai);
            float as_in = 0.2f / (nx * sqrtf(curv) + 1e-6f);        // 2*min_radius
            as_in = fminf(fmaxf(as_in, -1.0f + 1e-6f), 1.0f - 1e-6f);
            float ap = asinf(as_in);
            local += fmaxf(ang - ap, 0.0f);
        }
    }
    if (lane == 0) atomicAdd(ent_acc, local);
}

// ---- fused finalize: CE assembly + output write, single block ----
__global__ __launch_bounds__(1024) void finalize_kernel(
    const float* __restrict__ rsum_e, const float* __restrict__ rsum_t,
    const float* __restrict__ csum_e, const float* __restrict__ csum_t,
    const int* __restrict__ labels, const int* __restrict__ hist,
    const float* __restrict__ ent_acc, float* __restrict__ out) {
    __shared__ float red[16];
    int tid = threadIdx.x;
    float part = 0.0f;
    for (int n = tid; n < B_SZ; n += 1024) {
        float Sn = (float)hist[labels[n]];
        #pragma unroll
        for (int p = 0; p < 3; ++p) {
            part += Sn * (__logf(rsum_e[p * B_SZ + n]) - SHIFT) - rsum_t[p * B_SZ + n];
            part += Sn * (__logf(csum_e[p * B_SZ + n]) - SHIFT) - csum_t[p * B_SZ + n];
        }
    }
    #pragma unroll
    for (int m = 1; m < 64; m <<= 1) part += __shfl_xor(part, m);
    if ((tid & 63) == 0) red[tid >> 6] = part;
    __syncthreads();
    if (tid == 0) {
        float ce = 0.0f;
        #pragma unroll
        for (int i = 0; i < 16; ++i) ce += red[i];
        float contr = ce / (6.0f * (float)B_SZ);
        float ent = ent_acc[0] / (float)B_SZ;
        out[0] = contr + 0.2f * ent;
        out[1] = contr;
        out[2] = ent;
    }
}

// ---- workspace layout (bytes) ----
//   0        : bf16 feats, 3*4096*512*2 = 12,582,912
//   12582912 : times[3][4096] f32        (49,152)
//   12632064 : norms[3][4096] f32        (49,152)
//   12681216 : rsum_e[3][4096] f32       (49,152)   <- zeroed each launch
//   12730368 : rsum_t[3][4096] f32       (49,152)
//   12779520 : csum_e[3][4096] f32       (49,152)
//   12828672 : csum_t[3][4096] f32       (49,152)
//   12877824 : hist[512] int             (2,048)
//   12879872 : ent_acc f32
extern "C" void kernel_launch(void* const* d_in, const int* in_sizes, int n_in,
                              void* d_out, int out_size, void* d_ws, size_t ws_size,
                              hipStream_t stream) {
    const float* img    = (const float*)d_in[0];
    const float* dna    = (const float*)d_in[1];
    const float* txt    = (const float*)d_in[2];
    const int*   labels = (const int*)d_in[3];
    const float* ls     = (const float*)d_in[4];
    const float* curv   = (const float*)d_in[5];

    char* ws = (char*)d_ws;
    u16*   bf     = (u16*)ws;
    float* times  = (float*)(ws + 12582912);
    float* norms  = (float*)(ws + 12632064);
    float* rsum_e = (float*)(ws + 12681216);
    float* rsum_t = (float*)(ws + 12730368);
    float* csum_e = (float*)(ws + 12779520);
    float* csum_t = (float*)(ws + 12828672);
    int*   hist   = (int*)  (ws + 12877824);
    float* ent_acc= (float*)(ws + 12879872);

    hipMemsetAsync(ws + 12681216, 0, 198664, stream);  // accumulators + hist + scalar

    prep_kernel<<<3072, 256, 0, stream>>>(img, dna, txt, curv, labels, hist, bf, times, norms);
    dim3 g(32, 32, 3);
    gemm_epi_kernel<<<g, 256, 0, stream>>>(bf, times, labels, ls, curv,
                                           rsum_e, rsum_t, csum_e, csum_t);
    entail_kernel<<<256, 256, 0, stream>>>(dna, img, times, norms, curv, ent_acc);
    finalize_kernel<<<1, 1024, 0, stream>>>(rsum_e, rsum_t, csum_e, csum_t,
                                            labels, hist, ent_acc, (float*)d_out);
}